// Round 5
// baseline (995.819 us; speedup 1.0000x reference)
//
#include <hip/hip_runtime.h>
#include <hip/hip_bf16.h>
#include <math.h>

#define MDIM 2048
#define KDIM 1024
#define BIGF 1e9f
#define NSTRIP 16
#define DELTA 192          // skew in steps; 6 phases of 32 exactly
#define NPH 158            // ((DELTA*15 + 2174) >> 5) + 1

typedef unsigned short ushort;
typedef unsigned int uint;
typedef __attribute__((ext_vector_type(8))) short short8v;
typedef __attribute__((ext_vector_type(8))) ushort ushort8v;
typedef __attribute__((ext_vector_type(4))) float f32x4;
typedef __attribute__((ext_vector_type(4))) float fvec4;

// ---------------- row normalization: one wave per row, emits bf16 ----------
__device__ __forceinline__ ushort f2bf(float f) {
  uint b = __builtin_bit_cast(uint, f);
  b += 0x7FFFu + ((b >> 16) & 1u);
  return (ushort)(b >> 16);
}

__global__ __launch_bounds__(256) void normalize_rows(
    const float* __restrict__ x, const float* __restrict__ y,
    ushort* __restrict__ xb, ushort* __restrict__ yb) {
  int wave = (blockIdx.x * blockDim.x + threadIdx.x) >> 6;
  int lane = threadIdx.x & 63;
  const float* src;
  ushort* dst;
  int row;
  if (wave < MDIM) { src = x; dst = xb; row = wave; }
  else             { src = y; dst = yb; row = wave - MDIM; }
  const float* r = src + (size_t)row * KDIM;
  ushort* w = dst + (size_t)row * KDIM;
  float ss = 0.f;
  for (int c = lane * 4; c < KDIM; c += 64 * 4) {
    float4 v = *(const float4*)&r[c];
    ss += v.x * v.x + v.y * v.y + v.z * v.z + v.w * v.w;
  }
  #pragma unroll
  for (int off = 32; off; off >>= 1) ss += __shfl_xor(ss, off, 64);
  float inv = 1.f / fmaxf(sqrtf(ss), 1e-12f);
  for (int c = lane * 4; c < KDIM; c += 64 * 4) {
    float4 v = *(const float4*)&r[c];
    uint2 o;
    o.x = (uint)f2bf(v.x * inv) | ((uint)f2bf(v.y * inv) << 16);
    o.y = (uint)f2bf(v.z * inv) | ((uint)f2bf(v.w * inv) << 16);
    *(uint2*)&w[c] = o;
  }
}

// ------------- cost GEMM (bf16 MFMA): C' = (1 - A.B^T) * kexp -------------
__global__ __launch_bounds__(256) void gemm_cost_mfma(
    const ushort* __restrict__ xb, const ushort* __restrict__ yb,
    float* __restrict__ cost_base, const float* __restrict__ gamma_p) {
  int z = blockIdx.z;
  const ushort* A = (z == 2) ? yb : xb;
  const ushort* B = (z == 0) ? yb : ((z == 1) ? xb : yb);
  float* C = cost_base + (size_t)z * MDIM * MDIM;
  float g = fmaxf(fabsf(gamma_p[0]), 1e-4f);
  float kexp = 1.44269504089f / g;

  __shared__ ushort As[128 * 64];
  __shared__ ushort Bs[128 * 64];

  int tid = threadIdx.x;
  int w = tid >> 6, l = tid & 63;
  int wr = w >> 1, wc = w & 1;
  int abase = blockIdx.y * 128;
  int bbase = blockIdx.x * 128;

  f32x4 acc[4][4] = {};

  for (int k0 = 0; k0 < KDIM; k0 += 64) {
    ushort8v va[4], vb[4];
    #pragma unroll
    for (int q = 0; q < 4; ++q) {
      int slot = q * 256 + tid;
      int row = slot >> 3, sc = slot & 7;
      va[q] = *(const ushort8v*)&A[(size_t)(abase + row) * KDIM + k0 + sc * 8];
      vb[q] = *(const ushort8v*)&B[(size_t)(bbase + row) * KDIM + k0 + sc * 8];
    }
    __syncthreads();
    #pragma unroll
    for (int q = 0; q < 4; ++q) {
      int slot = q * 256 + tid;
      int row = slot >> 3, sc = slot & 7;
      int off = row * 64 + ((sc ^ (row & 7)) << 3);
      *(ushort8v*)&As[off] = va[q];
      *(ushort8v*)&Bs[off] = vb[q];
    }
    __syncthreads();
    #pragma unroll
    for (int kk = 0; kk < 2; ++kk) {
      short8v af[4], bf[4];
      #pragma unroll
      for (int m = 0; m < 4; ++m) {
        int row = wr * 64 + m * 16 + (l & 15);
        int kg = kk * 4 + (l >> 4);
        af[m] = *(const short8v*)&As[row * 64 + ((kg ^ (row & 7)) << 3)];
      }
      #pragma unroll
      for (int n = 0; n < 4; ++n) {
        int row = wc * 64 + n * 16 + (l & 15);
        int kg = kk * 4 + (l >> 4);
        bf[n] = *(const short8v*)&Bs[row * 64 + ((kg ^ (row & 7)) << 3)];
      }
      #pragma unroll
      for (int m = 0; m < 4; ++m)
        #pragma unroll
        for (int n = 0; n < 4; ++n)
          acc[m][n] = __builtin_amdgcn_mfma_f32_16x16x32_bf16(
              af[m], bf[n], acc[m][n], 0, 0, 0);
    }
  }
  #pragma unroll
  for (int m = 0; m < 4; ++m) {
    int row0 = abase + wr * 64 + m * 16 + (l >> 4) * 4;
    #pragma unroll
    for (int n = 0; n < 4; ++n) {
      int col = bbase + wc * 64 + n * 16 + (l & 15);
      f32x4 v = acc[m][n];
      #pragma unroll
      for (int r = 0; r < 4; ++r)
        C[(size_t)(row0 + r) * MDIM + col] = (1.0f - v[r]) * kexp;
    }
  }
}

// ---------------- soft-DTW: LDS-staged register wavefront ----------------
__device__ __forceinline__ float fexp2(float x) { return __builtin_amdgcn_exp2f(x); }
__device__ __forceinline__ float flog2(float x) { return __builtin_amdgcn_logf(x); }

__device__ __forceinline__ float ror1(float v) {
  int r = __builtin_amdgcn_update_dpp(__builtin_bit_cast(int, v),
                                      __builtin_bit_cast(int, v),
                                      0x13C /*wave_ror:1*/, 0xF, 0xF, false);
  return __builtin_bit_cast(float, r);
}

__device__ __forceinline__ float aload(const float* p) {
  return __hip_atomic_load(p, __ATOMIC_RELAXED, __HIP_MEMORY_SCOPE_AGENT);
}

// one 16-step group; lane l owns rows l (chain0) and 64+l (chain1);
// chain1 runs 64 cols behind chain0. Cost read from LDS ring (conflict-free).
template <bool FIRST, bool EDGE>
__device__ __forceinline__ void dp_group16(
    float& o0, float& o1, float& d0, float& d1, float& cc0, float& cc1,
    float (&bq)[16], const float* __restrict__ bp, float* __restrict__ bw,
    const float* smem, int cb16, int lane, int ln32) {
  const bool l0 = (lane == 0);
  const bool l63 = (lane == 63);
  const int K = cb16 - lane;
  float h0, h1, h2, h3;
  #pragma unroll
  for (int u = 0; u < 16; ++u) {
    // prefetch next step's cost from LDS (consumed next iteration)
    int nrel = K + u + 1;
    int xx = nrel & 31;
    int sl = (nrel >> 5) & 3;
    float p0 = smem[(sl << 11) + ln32 + xx];
    float p1 = smem[8192 + (((sl ^ 2) & 3) << 11) + ln32 + xx];
    // neighbors via wave rotate
    float t0 = ror1(o0);
    float t1 = ror1(o1);
    float av0 = FIRST ? (l0 ? BIGF : t0) : (l0 ? bq[u] : t0);
    float av1 = l0 ? t0 : t1;
    // softmin over {diag, above, left} in log2 units
    float mn0 = fminf(fminf(d0, av0), o0);
    float mx0 = fmaxf(fmaxf(d0, av0), o0);
    float md0;
    asm("v_med3_f32 %0, %1, %2, %3" : "=v"(md0) : "v"(d0), "v"(av0), "v"(o0));
    float mn1 = fminf(fminf(d1, av1), o1);
    float mx1 = fmaxf(fmaxf(d1, av1), o1);
    float md1;
    asm("v_med3_f32 %0, %1, %2, %3" : "=v"(md1) : "v"(d1), "v"(av1), "v"(o1));
    float e0 = 1.0f + fexp2(mn0 - md0) + fexp2(mn0 - mx0);
    float e1 = 1.0f + fexp2(mn1 - md1) + fexp2(mn1 - mx1);
    float n0 = cc0 + (mn0 - flog2(e0));
    float n1 = cc1 + (mn1 - flog2(e1));
    if (EDGE) {
      int c0 = K + u;
      int c1 = c0 - 64;
      n0 = ((unsigned)c0 < (unsigned)MDIM) ? n0 : BIGF;
      bool v1 = ((unsigned)c1 < (unsigned)MDIM);
      n1 = v1 ? n1 : BIGF;
      if (l63 && v1) bw[c1] = n1;
    } else {
      if ((u & 3) == 0) h0 = n1;
      else if ((u & 3) == 1) h1 = n1;
      else if ((u & 3) == 2) h2 = n1;
      else h3 = n1;
      if ((u & 3) == 3 && l63) {
        float* a = &bw[cb16 + u - 130];
        a[0] = h0; a[1] = h1; a[2] = h2; a[3] = h3;
      }
    }
    d0 = av0; d1 = av1; o0 = n0; o1 = n1;
    cc0 = p0; cc1 = p1;
    // broadcast refill of predecessor bottom row (next group's values)
    if (!FIRST) {
      int qb = cb16 + u + 16;
      if (EDGE) qb = min(max(qb, 0), MDIM - 1);
      bq[u] = aload(&bp[qb]);
    }
  }
}

template <bool FIRST, bool EDGE>
__device__ __forceinline__ void dp_phase(
    float& o0, float& o1, float& d0, float& d1, float& cc0, float& cc1,
    float (&bq)[16], const float* __restrict__ bp, float* __restrict__ bw,
    float* smem, const float* __restrict__ cost_s,
    int cb, int lane, int ln32, bool do_stage, int slotA, int slotB) {
  fvec4 sA[8], sB[8];
  const int f4c = lane & 7;
  const int rsub = lane >> 3;
  if (do_stage) {  // coalesced loads for next chunks (chain0: cb+32, chain1: cb-32)
    int cA = min(max(cb + 32 + f4c * 4, 0), MDIM - 4);
    int cB = min(max(cb - 32 + f4c * 4, 0), MDIM - 4);
    #pragma unroll
    for (int k = 0; k < 8; ++k) {
      sA[k] = *(const fvec4*)&cost_s[(size_t)(k * 8 + rsub) * MDIM + cA];
      sB[k] = *(const fvec4*)&cost_s[(size_t)(64 + k * 8 + rsub) * MDIM + cB];
    }
  }
  dp_group16<FIRST, EDGE>(o0, o1, d0, d1, cc0, cc1, bq, bp, bw, smem,
                          cb, lane, ln32);
  if (do_stage) {  // target slots were last read 2 phases ago -> free now
    #pragma unroll
    for (int k = 0; k < 8; ++k) {
      int ro = (k * 8 + rsub) * 32 + f4c * 4;
      *(fvec4*)&smem[slotA * 2048 + ro] = sA[k];
      *(fvec4*)&smem[8192 + slotB * 2048 + ro] = sB[k];
    }
  }
  dp_group16<FIRST, EDGE>(o0, o1, d0, d1, cc0, cc1, bq, bp, bw, smem,
                          cb + 16, lane, ln32);
}

__global__ __launch_bounds__(64, 1) void softdtw_dp(
    const float* __restrict__ cost_base, float* __restrict__ bottom,
    int* __restrict__ flags) {
  extern __shared__ float smem[];  // 2 chains x 4 slots x (64 rows x 32 cols) f32 = 64KB
  const int bid = blockIdx.x;
  const int z = bid & 7;           // XCD grouping: same matrix -> same XCD
  if (z >= 3) return;
  const int s = bid >> 3;
  const int lane = threadIdx.x;
  const int ln32 = lane * 32;

  const float* cost = cost_base + (size_t)z * MDIM * MDIM;
  const float* cost_s = cost + (size_t)s * 128 * MDIM;
  float* bot_z = bottom + (size_t)z * NSTRIP * MDIM;
  const float* bp = bot_z + (size_t)(s > 0 ? s - 1 : 0) * MDIM;
  float* bw = bot_z + (size_t)s * MDIM;
  int* predf = &flags[z * NSTRIP + (s > 0 ? s - 1 : 0)];
  int* myf = &flags[z * NSTRIP + s];

  const int pS0 = 6 * s;                       // DELTA/32 * s (exact)
  const int pS1 = (DELTA * s + 2174) >> 5;

  // prestage: chain0 chunks q=-2..0 (cols -64..31), chain1 q=-4..-2 (cols -128..-33)
  {
    const int f4c = lane & 7;
    const int rsub = lane >> 3;
    #pragma unroll
    for (int q = 0; q < 3; ++q) {
      int colA = (q - 2) * 32;        // -64, -32, 0
      int colB = (q - 4) * 32;        // -128, -96, -64
      int cA = min(max(colA + f4c * 4, 0), MDIM - 4);
      int cB = min(max(colB + f4c * 4, 0), MDIM - 4);
      int slA = (q - 2) & 3;          // 2, 3, 0
      int slB = (q - 4) & 3;          // 0, 1, 2
      fvec4 vA[8], vB[8];
      #pragma unroll
      for (int k = 0; k < 8; ++k) {
        vA[k] = *(const fvec4*)&cost_s[(size_t)(k * 8 + rsub) * MDIM + cA];
        vB[k] = *(const fvec4*)&cost_s[(size_t)(64 + k * 8 + rsub) * MDIM + cB];
      }
      #pragma unroll
      for (int k = 0; k < 8; ++k) {
        int ro = (k * 8 + rsub) * 32 + f4c * 4;
        *(fvec4*)&smem[slA * 2048 + ro] = vA[k];
        *(fvec4*)&smem[8192 + slB * 2048 + ro] = vB[k];
      }
    }
  }

  float o0 = BIGF, o1 = BIGF, d0 = BIGF, d1 = BIGF, cc0 = 0.f, cc1 = 0.f;
  float bq[16];
  int pcache = 0;

  for (int p = 0; p < NPH; ++p) {
    if (s > 0 && pcache < p) {
      int it = 0;
      do {
        pcache = __hip_atomic_load(predf, __ATOMIC_ACQUIRE,
                                   __HIP_MEMORY_SCOPE_AGENT);
        if (pcache < p) __builtin_amdgcn_s_sleep(1);
      } while (pcache < p && ++it < (1 << 22));
    }
    if (p >= pS0 && p <= pS1) {
      const int dq = p - pS0;
      const int cb = dq << 5;
      if (p == pS0) {
        o0 = o1 = d1 = BIGF;
        d0 = (s == 0 && lane == 0) ? 0.0f : BIGF;
        int nrel = -lane;
        int xx = nrel & 31;
        int sl = (nrel >> 5) & 3;
        cc0 = smem[(sl << 11) + ln32 + xx];
        cc1 = smem[8192 + (((sl ^ 2) & 3) << 11) + ln32 + xx];
        if (s > 0) {
          #pragma unroll
          for (int u = 0; u < 16; ++u) bq[u] = aload(&bp[u]);
        }
      }
      const bool do_stage = p < pS1;
      const bool interior = (cb >= 128) && (cb <= 2016);
      const int slotA = (dq + 1) & 3;
      const int slotB = (dq - 1) & 3;
      if (s == 0) {
        if (interior)
          dp_phase<true, false>(o0, o1, d0, d1, cc0, cc1, bq, bp, bw, smem,
                                cost_s, cb, lane, ln32, do_stage, slotA, slotB);
        else
          dp_phase<true, true>(o0, o1, d0, d1, cc0, cc1, bq, bp, bw, smem,
                               cost_s, cb, lane, ln32, do_stage, slotA, slotB);
      } else {
        if (interior)
          dp_phase<false, false>(o0, o1, d0, d1, cc0, cc1, bq, bp, bw, smem,
                                 cost_s, cb, lane, ln32, do_stage, slotA, slotB);
        else
          dp_phase<false, true>(o0, o1, d0, d1, cc0, cc1, bq, bp, bw, smem,
                                cost_s, cb, lane, ln32, do_stage, slotA, slotB);
      }
    }
    if (lane == 63)
      __hip_atomic_store(myf, p + 1, __ATOMIC_RELEASE,
                         __HIP_MEMORY_SCOPE_AGENT);
  }
}

__global__ void dtw_init(int* __restrict__ flags) {
  if (threadIdx.x < 3 * NSTRIP) flags[threadIdx.x] = 0;
}

__global__ void combine(const float* __restrict__ bottom,
                        const float* __restrict__ gamma_p,
                        float* __restrict__ out) {
  float g = fmaxf(fabsf(gamma_p[0]), 1e-4f);
  float glog = 0.69314718056f * g;
  float b0 = bottom[0 * NSTRIP * MDIM + 15 * MDIM + 2047];
  float b1 = bottom[1 * NSTRIP * MDIM + 15 * MDIM + 2047];
  float b2 = bottom[2 * NSTRIP * MDIM + 15 * MDIM + 2047];
  out[0] = (b0 - 0.5f * (b1 + b2)) * glog;
}

extern "C" void kernel_launch(void* const* d_in, const int* in_sizes, int n_in,
                              void* d_out, int out_size, void* d_ws, size_t ws_size,
                              hipStream_t stream) {
  const float* x = (const float*)d_in[0];
  const float* y = (const float*)d_in[1];
  const float* gamma = (const float*)d_in[2];
  float* out = (float*)d_out;

  char* ws = (char*)d_ws;
  ushort* xb = (ushort*)ws;                                // 4 MB
  ushort* yb = (ushort*)(ws + (size_t)4 * 1024 * 1024);    // 4 MB
  float* cost = (float*)(ws + (size_t)8 * 1024 * 1024);    // 48 MB
  float* bottom = (float*)(ws + (size_t)56 * 1024 * 1024); // 384 KB
  int* flags = (int*)(ws + (size_t)57 * 1024 * 1024);      // 192 B

  normalize_rows<<<(2 * MDIM) / 4, 256, 0, stream>>>(x, y, xb, yb);

  dim3 ggrid(MDIM / 128, MDIM / 128, 3);
  gemm_cost_mfma<<<ggrid, 256, 0, stream>>>(xb, yb, cost, gamma);

  dtw_init<<<1, 64, 0, stream>>>(flags);

  softdtw_dp<<<128, 64, 65536, stream>>>(cost, bottom, flags);

  combine<<<1, 1, 0, stream>>>(bottom, gamma, out);
}

// Round 7
// 886.965 us; speedup vs baseline: 1.1227x; 1.1227x over previous
//
#include <hip/hip_runtime.h>
#include <hip/hip_bf16.h>
#include <math.h>

#define MDIM 2048
#define KDIM 1024
#define BIGF 1e9f
#define NSTRIP 32   // strips per matrix, 64 rows each (1 row per lane)
// DELTA = 128 steps = 2 phases of 64. Strip s active phases [2s, 2s+32].

typedef unsigned short ushort;
typedef unsigned int uint;
typedef __attribute__((ext_vector_type(8))) short short8v;
typedef __attribute__((ext_vector_type(8))) ushort ushort8v;
typedef __attribute__((ext_vector_type(4))) float f32x4;
typedef __attribute__((ext_vector_type(4), aligned(4))) float f4u;

// ---------------- row normalization: one wave per row, emits bf16 ----------
__device__ __forceinline__ ushort f2bf(float f) {
  uint b = __builtin_bit_cast(uint, f);
  b += 0x7FFFu + ((b >> 16) & 1u);
  return (ushort)(b >> 16);
}

__global__ __launch_bounds__(256) void normalize_rows(
    const float* __restrict__ x, const float* __restrict__ y,
    ushort* __restrict__ xb, ushort* __restrict__ yb) {
  int wave = (blockIdx.x * blockDim.x + threadIdx.x) >> 6;
  int lane = threadIdx.x & 63;
  const float* src;
  ushort* dst;
  int row;
  if (wave < MDIM) { src = x; dst = xb; row = wave; }
  else             { src = y; dst = yb; row = wave - MDIM; }
  const float* r = src + (size_t)row * KDIM;
  ushort* w = dst + (size_t)row * KDIM;
  float ss = 0.f;
  for (int c = lane * 4; c < KDIM; c += 64 * 4) {
    float4 v = *(const float4*)&r[c];
    ss += v.x * v.x + v.y * v.y + v.z * v.z + v.w * v.w;
  }
  #pragma unroll
  for (int off = 32; off; off >>= 1) ss += __shfl_xor(ss, off, 64);
  float inv = 1.f / fmaxf(sqrtf(ss), 1e-12f);
  for (int c = lane * 4; c < KDIM; c += 64 * 4) {
    float4 v = *(const float4*)&r[c];
    uint2 o;
    o.x = (uint)f2bf(v.x * inv) | ((uint)f2bf(v.y * inv) << 16);
    o.y = (uint)f2bf(v.z * inv) | ((uint)f2bf(v.w * inv) << 16);
    *(uint2*)&w[c] = o;
  }
}

// ------------- cost GEMM (bf16 MFMA): C' = (1 - A.B^T) * kexp -------------
__global__ __launch_bounds__(256) void gemm_cost_mfma(
    const ushort* __restrict__ xb, const ushort* __restrict__ yb,
    float* __restrict__ cost_base, const float* __restrict__ gamma_p) {
  int z = blockIdx.z;
  const ushort* A = (z == 2) ? yb : xb;
  const ushort* B = (z == 0) ? yb : ((z == 1) ? xb : yb);
  float* C = cost_base + (size_t)z * MDIM * MDIM;
  float g = fmaxf(fabsf(gamma_p[0]), 1e-4f);
  float kexp = 1.44269504089f / g;

  __shared__ ushort As[128 * 64];
  __shared__ ushort Bs[128 * 64];

  int tid = threadIdx.x;
  int w = tid >> 6, l = tid & 63;
  int wr = w >> 1, wc = w & 1;
  int abase = blockIdx.y * 128;
  int bbase = blockIdx.x * 128;

  f32x4 acc[4][4] = {};

  for (int k0 = 0; k0 < KDIM; k0 += 64) {
    ushort8v va[4], vb[4];
    #pragma unroll
    for (int q = 0; q < 4; ++q) {
      int slot = q * 256 + tid;
      int row = slot >> 3, sc = slot & 7;
      va[q] = *(const ushort8v*)&A[(size_t)(abase + row) * KDIM + k0 + sc * 8];
      vb[q] = *(const ushort8v*)&B[(size_t)(bbase + row) * KDIM + k0 + sc * 8];
    }
    __syncthreads();
    #pragma unroll
    for (int q = 0; q < 4; ++q) {
      int slot = q * 256 + tid;
      int row = slot >> 3, sc = slot & 7;
      int off = row * 64 + ((sc ^ (row & 7)) << 3);
      *(ushort8v*)&As[off] = va[q];
      *(ushort8v*)&Bs[off] = vb[q];
    }
    __syncthreads();
    #pragma unroll
    for (int kk = 0; kk < 2; ++kk) {
      short8v af[4], bf[4];
      #pragma unroll
      for (int m = 0; m < 4; ++m) {
        int row = wr * 64 + m * 16 + (l & 15);
        int kg = kk * 4 + (l >> 4);
        af[m] = *(const short8v*)&As[row * 64 + ((kg ^ (row & 7)) << 3)];
      }
      #pragma unroll
      for (int n = 0; n < 4; ++n) {
        int row = wc * 64 + n * 16 + (l & 15);
        int kg = kk * 4 + (l >> 4);
        bf[n] = *(const short8v*)&Bs[row * 64 + ((kg ^ (row & 7)) << 3)];
      }
      #pragma unroll
      for (int m = 0; m < 4; ++m)
        #pragma unroll
        for (int n = 0; n < 4; ++n)
          acc[m][n] = __builtin_amdgcn_mfma_f32_16x16x32_bf16(
              af[m], bf[n], acc[m][n], 0, 0, 0);
    }
  }
  #pragma unroll
  for (int m = 0; m < 4; ++m) {
    int row0 = abase + wr * 64 + m * 16 + (l >> 4) * 4;
    #pragma unroll
    for (int n = 0; n < 4; ++n) {
      int col = bbase + wc * 64 + n * 16 + (l & 15);
      f32x4 v = acc[m][n];
      #pragma unroll
      for (int r = 0; r < 4; ++r)
        C[(size_t)(row0 + r) * MDIM + col] = (1.0f - v[r]) * kexp;
    }
  }
}

// ---------------- soft-DTW: pure-register wavefront ----------------
__device__ __forceinline__ float fexp2(float x) { return __builtin_amdgcn_exp2f(x); }
__device__ __forceinline__ float flog2(float x) { return __builtin_amdgcn_logf(x); }

__device__ __forceinline__ float shr1(float v) {  // lane i <- lane i-1
  int r = __builtin_amdgcn_update_dpp(__builtin_bit_cast(int, v),
                                      __builtin_bit_cast(int, v),
                                      0x138 /*wave_shr:1*/, 0xF, 0xF, false);
  return __builtin_bit_cast(float, r);
}

__device__ __forceinline__ float aload(const float* p) {
  return __hip_atomic_load(p, __ATOMIC_RELAXED, __HIP_MEMORY_SCOPE_AGENT);
}

// interior staging: no clamps needed (base = cb+64-lane >= 1, max col <= 2047)
__device__ __forceinline__ void stage(f4u (&buf)[16],
                                      const float* __restrict__ crow, int base) {
  #pragma unroll
  for (int k = 0; k < 16; ++k)
    buf[k] = *(const f4u*)&crow[base + 4 * k];
}

// edge staging: exact per-element clamped loads (only 2 phases per strip)
__device__ __forceinline__ void stage_edge(f4u (&buf)[16],
                                           const float* __restrict__ crow,
                                           int base) {
  #pragma unroll
  for (int k = 0; k < 16; ++k)
    #pragma unroll
    for (int j = 0; j < 4; ++j) {
      int col = min(max(base + 4 * k + j, 0), MDIM - 1);
      buf[k][j] = crow[col];
    }
}

// one 64-step phase; lane l owns cost-row (64s + l); col at step u: cb+u-lane.
template <bool FIRST, bool EDGE>
__device__ __forceinline__ void phase_body(
    float& o, float& d, float bqv, const f4u (&cur)[16],
    int cb, int lane, float* __restrict__ bw) {
  const bool l0 = (lane == 0);
  const bool l63 = (lane == 63);
  float h0, h1, h2, h3;
  #pragma unroll
  for (int u = 0; u < 64; ++u) {
    float t = shr1(o);           // above = row-1's value at same col (prev step)
    float av;
    if (FIRST) {
      av = l0 ? BIGF : t;
    } else {
      float rv = __builtin_bit_cast(
          float, __builtin_amdgcn_readlane(__builtin_bit_cast(int, bqv), u));
      av = l0 ? rv : t;
    }
    float mn, md, mx;
    asm("v_min3_f32 %0, %1, %2, %3" : "=v"(mn) : "v"(d), "v"(av), "v"(o));
    asm("v_med3_f32 %0, %1, %2, %3" : "=v"(md) : "v"(d), "v"(av), "v"(o));
    asm("v_max3_f32 %0, %1, %2, %3" : "=v"(mx) : "v"(d), "v"(av), "v"(o));
    float e = 1.0f + fexp2(mn - md) + fexp2(mn - mx);
    float n = cur[u >> 2][u & 3] + (mn - flog2(e));
    if (EDGE) {
      int c = cb + u - lane;
      bool valid = ((unsigned)c < (unsigned)MDIM);
      n = valid ? n : BIGF;
      if (l63 && valid) bw[c] = n;
    } else {
      if ((u & 3) == 0) h0 = n;
      else if ((u & 3) == 1) h1 = n;
      else if ((u & 3) == 2) h2 = n;
      else {
        h3 = n;
        if (l63) *(f4u*)&bw[cb + u - 66] = (f4u){h0, h1, h2, h3};
      }
    }
    d = av;
    o = n;
  }
}

__global__ __launch_bounds__(64, 1) void softdtw_dp(
    const float* __restrict__ cost_base, float* __restrict__ bottom,
    int* __restrict__ flags) {
  const int bid = blockIdx.x;
  const int z = bid & 7;          // XCD grouping heuristic
  if (z >= 3) return;
  const int s = bid >> 3;         // strip 0..31
  const int lane = threadIdx.x;

  const float* cost = cost_base + (size_t)z * MDIM * MDIM;
  const float* crow = cost + (size_t)(s * 64 + lane) * MDIM;
  float* bot_z = bottom + (size_t)z * NSTRIP * MDIM;
  const float* bp = bot_z + (size_t)(s > 0 ? s - 1 : 0) * MDIM;
  float* bw = bot_z + (size_t)s * MDIM;
  int* predf = &flags[z * NSTRIP + (s > 0 ? s - 1 : 0)];
  int* myf = &flags[z * NSTRIP + s];

  const int pS0 = 2 * s;
  const int pS1 = 2 * s + 32;

  f4u bufA[16], bufB[16];
  stage_edge(bufA, crow, -lane);  // phase dq=0 (cb=0) window

  float o = BIGF;
  float d = (s == 0 && lane == 0) ? 0.0f : BIGF;  // seeds R[0,0]=0 via diag

  if (lane == 63 && s > 0)
    __hip_atomic_store(myf, pS0, __ATOMIC_RELEASE, __HIP_MEMORY_SCOPE_AGENT);

  int pcache = 0;
  for (int p = pS0; p <= pS1; ++p) {
    const int dq = p - pS0;
    const int cb = dq << 6;
    if (s > 0 && pcache < p) {
      int it = 0;
      do {
        pcache = __hip_atomic_load(predf, __ATOMIC_ACQUIRE,
                                   __HIP_MEMORY_SCOPE_AGENT);
        if (pcache < p) __builtin_amdgcn_s_sleep(1);
      } while (pcache < p && ++it < (1 << 22));
    }
    float bqv = 0.0f;
    if (s > 0) bqv = aload(&bp[min(cb + lane, MDIM - 1)]);
    // prefetch next phase's cost window into the OTHER buffer.
    // parity: even dq reads bufA, odd dq reads bufB -> prefetch target is
    // bufB when dq even, bufA when dq odd. (r6 bug: dq==31 wrote bufB while
    // reading bufB, clobbering the live window -> corrupted last 2 phases.)
    if (dq < 31) {
      if ((dq & 1) == 0) stage(bufB, crow, cb + 64 - lane);
      else               stage(bufA, crow, cb + 64 - lane);
    } else if (dq == 31) {
      stage_edge(bufA, crow, cb + 64 - lane);  // dq=32 (even) reads bufA
    }
    const bool edge = (dq == 0) || (dq == 32);
    if (s == 0) {
      if ((dq & 1) == 0) {
        if (edge) phase_body<true, true>(o, d, bqv, bufA, cb, lane, bw);
        else      phase_body<true, false>(o, d, bqv, bufA, cb, lane, bw);
      } else {
        phase_body<true, false>(o, d, bqv, bufB, cb, lane, bw);
      }
    } else {
      if ((dq & 1) == 0) {
        if (edge) phase_body<false, true>(o, d, bqv, bufA, cb, lane, bw);
        else      phase_body<false, false>(o, d, bqv, bufA, cb, lane, bw);
      } else {
        phase_body<false, false>(o, d, bqv, bufB, cb, lane, bw);
      }
    }
    if (lane == 63)
      __hip_atomic_store(myf, p + 1, __ATOMIC_RELEASE,
                         __HIP_MEMORY_SCOPE_AGENT);
  }
  if (lane == 63)
    __hip_atomic_store(myf, 1 << 20, __ATOMIC_RELEASE,
                       __HIP_MEMORY_SCOPE_AGENT);
}

__global__ void dtw_init(int* __restrict__ flags) {
  if (threadIdx.x < 3 * NSTRIP) flags[threadIdx.x] = 0;
}

__global__ void combine(const float* __restrict__ bottom,
                        const float* __restrict__ gamma_p,
                        float* __restrict__ out) {
  float g = fmaxf(fabsf(gamma_p[0]), 1e-4f);
  float glog = 0.69314718056f * g;   // unscale: V = V' * g * ln2
  float b0 = bottom[0 * NSTRIP * MDIM + (NSTRIP - 1) * MDIM + 2047];
  float b1 = bottom[1 * NSTRIP * MDIM + (NSTRIP - 1) * MDIM + 2047];
  float b2 = bottom[2 * NSTRIP * MDIM + (NSTRIP - 1) * MDIM + 2047];
  out[0] = (b0 - 0.5f * (b1 + b2)) * glog;
}

extern "C" void kernel_launch(void* const* d_in, const int* in_sizes, int n_in,
                              void* d_out, int out_size, void* d_ws, size_t ws_size,
                              hipStream_t stream) {
  const float* x = (const float*)d_in[0];
  const float* y = (const float*)d_in[1];
  const float* gamma = (const float*)d_in[2];
  float* out = (float*)d_out;

  char* ws = (char*)d_ws;
  ushort* xb = (ushort*)ws;                                // 4 MB
  ushort* yb = (ushort*)(ws + (size_t)4 * 1024 * 1024);    // 4 MB
  float* cost = (float*)(ws + (size_t)8 * 1024 * 1024);    // 48 MB
  float* bottom = (float*)(ws + (size_t)56 * 1024 * 1024); // 768 KB used
  int* flags = (int*)(ws + (size_t)59 * 1024 * 1024);      // 384 B

  normalize_rows<<<(2 * MDIM) / 4, 256, 0, stream>>>(x, y, xb, yb);

  dim3 ggrid(MDIM / 128, MDIM / 128, 3);
  gemm_cost_mfma<<<ggrid, 256, 0, stream>>>(xb, yb, cost, gamma);

  dtw_init<<<1, 128, 0, stream>>>(flags);

  softdtw_dp<<<256, 64, 0, stream>>>(cost, bottom, flags);

  combine<<<1, 1, 0, stream>>>(bottom, gamma, out);
}